// Round 3
// baseline (1425.170 us; speedup 1.0000x reference)
//
#include <hip/hip_runtime.h>
#include <hip/hip_bf16.h>
#include <stdint.h>

// Problem constants (B=4,S=2048 -> T=8192)
#define T_TOK 8192
#define H_DIM 1024
#define F_DIM 3584
#define E_NUM 8

// GEMM tiling
#define BM 128
#define BN 128
#define BK 32
#define LDT 40   // fallback-path padded LDS stride

typedef __attribute__((ext_vector_type(8))) short bf16x8;
typedef __attribute__((ext_vector_type(4))) float f32x4;
typedef __attribute__((ext_vector_type(4))) unsigned int u32x4;

__device__ __forceinline__ short f2bf(float f) {
    union { float f; uint32_t u; } v; v.f = f;
    uint32_t r = v.u + 0x7fffu + ((v.u >> 16) & 1u);   // RNE bf16
    return (short)(r >> 16);
}

// Pack 2 fp32 -> bf16x2 (round-to-nearest) via v_perm_b32.
__device__ __forceinline__ uint32_t pack_bf16x2(float a, float b) {
    union { float f; uint32_t u; } ua, ub;
    ua.f = a; ub.f = b;
    return __builtin_amdgcn_perm(ub.u + 0x8000u, ua.u + 0x8000u, 0x07060302u);
}

__device__ __forceinline__ void cvt_store16(const f32x4* v, short* dst) {
    uint32_t w[8];
    #pragma unroll
    for (int i = 0; i < 4; i++) {
        w[2*i]   = pack_bf16x2(v[i][0], v[i][1]);
        w[2*i+1] = pack_bf16x2(v[i][2], v[i][3]);
    }
    #pragma unroll
    for (int i = 0; i < 8; i++) ((uint32_t*)dst)[i] = w[i];
}

__device__ __forceinline__ void zero16_store(short* dst) {
    bf16x8 z;
    #pragma unroll
    for (int i = 0; i < 8; i++) z[i] = 0;
    *(bf16x8*)dst = z;
    *((bf16x8*)dst + 1) = z;
}

__device__ __forceinline__ void load16(f32x4* dst, const float* __restrict__ src) {
    const f32x4* p = (const f32x4*)src;
    #pragma unroll
    for (int i = 0; i < 4; i++) dst[i] = p[i];
}

// async global -> LDS, 16B per lane. lds dest must be wave-uniform base.
__device__ __forceinline__ void gload16(const unsigned short* g, unsigned short* l) {
    __builtin_amdgcn_global_load_lds(
        (const __attribute__((address_space(1))) void*)g,
        (__attribute__((address_space(3))) void*)l,
        16, 0, 0);
}

// ---------------------------------------------------------------------------
// Router: one wave per token, fp32 logits (exact top-2).
// ---------------------------------------------------------------------------
__global__ void router_kernel(const float* __restrict__ x,
                              const float* __restrict__ gate_w,
                              float* __restrict__ logits_out,
                              int* __restrict__ counts,
                              int* __restrict__ lists,
                              float* __restrict__ wgt) {
    int wave = (blockIdx.x * blockDim.x + threadIdx.x) >> 6;
    int lane = threadIdx.x & 63;
    if (wave >= T_TOK) return;
    const float* xr = x + (size_t)wave * H_DIM;

    float acc[E_NUM];
    #pragma unroll
    for (int e = 0; e < E_NUM; e++) acc[e] = 0.f;

    for (int i = lane; i < H_DIM; i += 64) {
        float xv = xr[i];
        #pragma unroll
        for (int e = 0; e < E_NUM; e++) acc[e] += xv * gate_w[e * H_DIM + i];
    }
    #pragma unroll
    for (int off = 32; off > 0; off >>= 1) {
        #pragma unroll
        for (int e = 0; e < E_NUM; e++) acc[e] += __shfl_xor(acc[e], off);
    }

    if (lane == 0) {
        int t = wave;
        #pragma unroll
        for (int e = 0; e < E_NUM; e++) logits_out[t * E_NUM + e] = acc[e];
        int i0 = 0; float v0 = acc[0];
        #pragma unroll
        for (int e = 1; e < E_NUM; e++) if (acc[e] > v0) { v0 = acc[e]; i0 = e; }
        int i1 = -1; float v1 = -1e30f;
        #pragma unroll
        for (int e = 0; e < E_NUM; e++) if (e != i0 && acc[e] > v1) { v1 = acc[e]; i1 = e; }
        float e1 = __expf(v1 - v0);
        float inv = 1.f / (1.f + e1);
        int a0 = 2 * t, a1 = 2 * t + 1;
        wgt[a0] = inv;
        wgt[a1] = e1 * inv;
        int p0 = atomicAdd(&counts[i0], 1);
        lists[i0 * T_TOK + p0] = a0;
        int p1 = atomicAdd(&counts[i1], 1);
        lists[i1 * T_TOK + p1] = a1;
    }
}

// ---------------------------------------------------------------------------
// fp32 -> bf16 bulk convert (8 elems/thread/iter, grid-stride).
// ---------------------------------------------------------------------------
__global__ void cvt_bf16_kernel(const float* __restrict__ in,
                                unsigned short* __restrict__ out, int n8) {
    int i = blockIdx.x * blockDim.x + threadIdx.x;
    int stride = gridDim.x * blockDim.x;
    for (; i < n8; i += stride) {
        const f32x4* p = (const f32x4*)in + 2 * (size_t)i;
        f32x4 v0 = p[0], v1 = p[1];
        u32x4 w;
        w[0] = pack_bf16x2(v0[0], v0[1]);
        w[1] = pack_bf16x2(v0[2], v0[3]);
        w[2] = pack_bf16x2(v1[0], v1[1]);
        w[3] = pack_bf16x2(v1[2], v1[3]);
        *(u32x4*)(out + 8 * (size_t)i) = w;
    }
}

// ---------------------------------------------------------------------------
// GEMM1 (bf16 path): hgate = silu(x@w1^T) * (x@w3^T), m97-style staging.
// LDS tiles [128][32] bf16 unpadded; global_load_lds 16B/lane.
// grid: (m-tiles, n-tiles, E) — m fastest for B-tile L2 reuse.
// ---------------------------------------------------------------------------
__global__ __launch_bounds__(256, 2)
void gemm1_bf(const unsigned short* __restrict__ xbf,
              const unsigned short* __restrict__ w1bf,
              const unsigned short* __restrict__ w3bf,
              const int* __restrict__ counts,
              const int* __restrict__ lists,
              const unsigned short* __restrict__ zbuf,
              unsigned short* __restrict__ hgate) {
    const int e = blockIdx.z;
    const int count = counts[e];
    const int mbase = blockIdx.x * BM;
    if (mbase >= count) return;
    const int nbase = blockIdx.y * BN;

    __shared__ unsigned short As[BM * BK];
    __shared__ unsigned short B1s[BN * BK];
    __shared__ unsigned short B3s[BN * BK];

    const int tid = threadIdx.x;
    const int lane = tid & 63;
    const int w = tid >> 6;
    const int sr0 = w * 16 + (lane >> 2);   // staging row, issue 0
    const int sr1 = 64 + sr0;               // staging row, issue 1
    const int chunk = lane & 3;             // 16B chunk within 64B row-slice

    const unsigned short* a0;
    const unsigned short* a1;
    {
        int m = mbase + sr0;
        a0 = (m < count) ? xbf + (size_t)(lists[e * T_TOK + m] >> 1) * H_DIM + chunk * 8
                         : zbuf + chunk * 8;
        m = mbase + sr1;
        a1 = (m < count) ? xbf + (size_t)(lists[e * T_TOK + m] >> 1) * H_DIM + chunk * 8
                         : zbuf + chunk * 8;
    }
    const unsigned short* b10 = w1bf + ((size_t)e * F_DIM + nbase + sr0) * H_DIM + chunk * 8;
    const unsigned short* b11 = w1bf + ((size_t)e * F_DIM + nbase + sr1) * H_DIM + chunk * 8;
    const unsigned short* b30 = w3bf + ((size_t)e * F_DIM + nbase + sr0) * H_DIM + chunk * 8;
    const unsigned short* b31 = w3bf + ((size_t)e * F_DIM + nbase + sr1) * H_DIM + chunk * 8;

    unsigned short* Al0  = &As[(size_t)(w * 16) * BK];
    unsigned short* Al1  = &As[(size_t)(64 + w * 16) * BK];
    unsigned short* B1l0 = &B1s[(size_t)(w * 16) * BK];
    unsigned short* B1l1 = &B1s[(size_t)(64 + w * 16) * BK];
    unsigned short* B3l0 = &B3s[(size_t)(w * 16) * BK];
    unsigned short* B3l1 = &B3s[(size_t)(64 + w * 16) * BK];

    const int wm = w >> 1, wn = w & 1;
    const int lr = lane & 15, lq = lane >> 4;

    f32x4 acc1[4][4], acc3[4][4];
    #pragma unroll
    for (int i = 0; i < 4; i++)
        #pragma unroll
        for (int j = 0; j < 4; j++) {
            acc1[i][j] = (f32x4){0.f, 0.f, 0.f, 0.f};
            acc3[i][j] = (f32x4){0.f, 0.f, 0.f, 0.f};
        }

    for (int k0 = 0; k0 < H_DIM; k0 += BK) {
        gload16(a0, Al0);  gload16(a1, Al1);
        gload16(b10, B1l0); gload16(b11, B1l1);
        gload16(b30, B3l0); gload16(b31, B3l1);
        a0 += BK; a1 += BK; b10 += BK; b11 += BK; b30 += BK; b31 += BK;
        __syncthreads();

        bf16x8 af[4];
        #pragma unroll
        for (int i = 0; i < 4; i++)
            af[i] = *(const bf16x8*)&As[(wm * 64 + i * 16 + lr) * BK + lq * 8];
        #pragma unroll
        for (int j = 0; j < 4; j++) {
            bf16x8 b1f = *(const bf16x8*)&B1s[(wn * 64 + j * 16 + lr) * BK + lq * 8];
            bf16x8 b3f = *(const bf16x8*)&B3s[(wn * 64 + j * 16 + lr) * BK + lq * 8];
            #pragma unroll
            for (int i = 0; i < 4; i++) {
                acc1[i][j] = __builtin_amdgcn_mfma_f32_16x16x32_bf16(af[i], b1f, acc1[i][j], 0, 0, 0);
                acc3[i][j] = __builtin_amdgcn_mfma_f32_16x16x32_bf16(af[i], b3f, acc3[i][j], 0, 0, 0);
            }
        }
        __syncthreads();
    }

    // Epilogue: silu(g)*u -> bf16 hgate rows. C/D: col=lane&15, row=lq*4+reg.
    #pragma unroll
    for (int i = 0; i < 4; i++) {
        #pragma unroll
        for (int rg = 0; rg < 4; rg++) {
            int mm = mbase + wm * 64 + i * 16 + lq * 4 + rg;
            if (mm >= count) continue;
            int a = lists[e * T_TOK + mm];
            unsigned short* hrow = hgate + (size_t)a * F_DIM + nbase;
            #pragma unroll
            for (int j = 0; j < 4; j++) {
                float g = acc1[i][j][rg];
                float u = acc3[i][j][rg];
                float s = (g / (1.f + __expf(-g))) * u;
                hrow[wn * 64 + j * 16 + lr] = (unsigned short)f2bf(s);
            }
        }
    }
}

// ---------------------------------------------------------------------------
// GEMM2 (bf16 path): out[t] += wgt * (hgate @ w2^T). Same staging structure.
// ---------------------------------------------------------------------------
__global__ __launch_bounds__(256, 3)
void gemm2_bf(const unsigned short* __restrict__ hgate,
              const unsigned short* __restrict__ w2bf,
              const int* __restrict__ counts,
              const int* __restrict__ lists,
              const float* __restrict__ wgt,
              const unsigned short* __restrict__ zbuf,
              float* __restrict__ out) {
    const int e = blockIdx.z;
    const int count = counts[e];
    const int mbase = blockIdx.x * BM;
    if (mbase >= count) return;
    const int nbase = blockIdx.y * BN;

    __shared__ unsigned short As[BM * BK];
    __shared__ unsigned short Bs[BN * BK];

    const int tid = threadIdx.x;
    const int lane = tid & 63;
    const int w = tid >> 6;
    const int sr0 = w * 16 + (lane >> 2);
    const int sr1 = 64 + sr0;
    const int chunk = lane & 3;

    const unsigned short* a0;
    const unsigned short* a1;
    {
        int m = mbase + sr0;
        a0 = (m < count) ? hgate + (size_t)lists[e * T_TOK + m] * F_DIM + chunk * 8
                         : zbuf + chunk * 8;
        m = mbase + sr1;
        a1 = (m < count) ? hgate + (size_t)lists[e * T_TOK + m] * F_DIM + chunk * 8
                         : zbuf + chunk * 8;
    }
    const unsigned short* b0 = w2bf + ((size_t)e * H_DIM + nbase + sr0) * F_DIM + chunk * 8;
    const unsigned short* b1 = w2bf + ((size_t)e * H_DIM + nbase + sr1) * F_DIM + chunk * 8;

    unsigned short* Al0 = &As[(size_t)(w * 16) * BK];
    unsigned short* Al1 = &As[(size_t)(64 + w * 16) * BK];
    unsigned short* Bl0 = &Bs[(size_t)(w * 16) * BK];
    unsigned short* Bl1 = &Bs[(size_t)(64 + w * 16) * BK];

    const int wm = w >> 1, wn = w & 1;
    const int lr = lane & 15, lq = lane >> 4;

    f32x4 acc[4][4];
    #pragma unroll
    for (int i = 0; i < 4; i++)
        #pragma unroll
        for (int j = 0; j < 4; j++) acc[i][j] = (f32x4){0.f, 0.f, 0.f, 0.f};

    for (int k0 = 0; k0 < F_DIM; k0 += BK) {
        gload16(a0, Al0); gload16(a1, Al1);
        gload16(b0, Bl0); gload16(b1, Bl1);
        a0 += BK; a1 += BK; b0 += BK; b1 += BK;
        __syncthreads();

        bf16x8 af[4];
        #pragma unroll
        for (int i = 0; i < 4; i++)
            af[i] = *(const bf16x8*)&As[(wm * 64 + i * 16 + lr) * BK + lq * 8];
        #pragma unroll
        for (int j = 0; j < 4; j++) {
            bf16x8 bf = *(const bf16x8*)&Bs[(wn * 64 + j * 16 + lr) * BK + lq * 8];
            #pragma unroll
            for (int i = 0; i < 4; i++)
                acc[i][j] = __builtin_amdgcn_mfma_f32_16x16x32_bf16(af[i], bf, acc[i][j], 0, 0, 0);
        }
        __syncthreads();
    }

    #pragma unroll
    for (int i = 0; i < 4; i++) {
        #pragma unroll
        for (int rg = 0; rg < 4; rg++) {
            int mm = mbase + wm * 64 + i * 16 + lq * 4 + rg;
            if (mm >= count) continue;
            int a = lists[e * T_TOK + mm];
            float wv = wgt[a];
            float* orow = out + (size_t)(a >> 1) * H_DIM + nbase;
            #pragma unroll
            for (int j = 0; j < 4; j++)
                atomicAdd(&orow[wn * 64 + j * 16 + lr], acc[i][j][rg] * wv);
        }
    }
}

// ===========================================================================
// Fallback path (fp32 inline-convert, R2 kernels) — used if ws too small.
// ===========================================================================
__global__ __launch_bounds__(256, 2)
void gemm1_f32(const float* __restrict__ x,
               const float* __restrict__ w1,
               const float* __restrict__ w3,
               const int* __restrict__ counts,
               const int* __restrict__ lists,
               unsigned short* __restrict__ hgate) {
    const int e = blockIdx.z;
    const int count = counts[e];
    const int mbase = blockIdx.y * BM;
    if (mbase >= count) return;
    const int nbase = blockIdx.x * BN;

    __shared__ short As[BM * LDT];
    __shared__ short B1s[BN * LDT];
    __shared__ short B3s[BN * LDT];

    const int tid = threadIdx.x;
    const int r = tid >> 1;
    const int half = tid & 1;

    const float* arow = nullptr;
    {
        int m = mbase + r;
        if (m < count) arow = x + (size_t)(lists[e * T_TOK + m] >> 1) * H_DIM;
    }
    const float* b1row = w1 + ((size_t)e * F_DIM + (nbase + r)) * H_DIM;
    const float* b3row = w3 + ((size_t)e * F_DIM + (nbase + r)) * H_DIM;

    const int lane = tid & 63;
    const int wid = tid >> 6;
    const int wm = wid >> 1, wn = wid & 1;
    const int lr = lane & 15, lq = lane >> 4;

    f32x4 acc1[4][4], acc3[4][4];
    #pragma unroll
    for (int i = 0; i < 4; i++)
        #pragma unroll
        for (int j = 0; j < 4; j++) {
            acc1[i][j] = (f32x4){0.f, 0.f, 0.f, 0.f};
            acc3[i][j] = (f32x4){0.f, 0.f, 0.f, 0.f};
        }

    f32x4 ap[4], b1p[4], b3p[4];
    {
        const int koff = half * 16;
        if (arow) load16(ap, arow + koff);
        load16(b1p, b1row + koff);
        load16(b3p, b3row + koff);
    }
    short* adst  = &As[r * LDT + half * 16];
    short* b1dst = &B1s[r * LDT + half * 16];
    short* b3dst = &B3s[r * LDT + half * 16];

    for (int k0 = 0; k0 < H_DIM; k0 += BK) {
        if (arow) cvt_store16(ap, adst); else zero16_store(adst);
        cvt_store16(b1p, b1dst);
        cvt_store16(b3p, b3dst);
        __syncthreads();
        int kn = k0 + BK;
        if (kn < H_DIM) {
            const int koff = kn + half * 16;
            if (arow) load16(ap, arow + koff);
            load16(b1p, b1row + koff);
            load16(b3p, b3row + koff);
        }
        bf16x8 af[4];
        #pragma unroll
        for (int i = 0; i < 4; i++)
            af[i] = *(const bf16x8*)&As[(wm * 64 + i * 16 + lr) * LDT + lq * 8];
        #pragma unroll
        for (int j = 0; j < 4; j++) {
            bf16x8 b1f = *(const bf16x8*)&B1s[(wn * 64 + j * 16 + lr) * LDT + lq * 8];
            bf16x8 b3f = *(const bf16x8*)&B3s[(wn * 64 + j * 16 + lr) * LDT + lq * 8];
            #pragma unroll
            for (int i = 0; i < 4; i++) {
                acc1[i][j] = __builtin_amdgcn_mfma_f32_16x16x32_bf16(af[i], b1f, acc1[i][j], 0, 0, 0);
                acc3[i][j] = __builtin_amdgcn_mfma_f32_16x16x32_bf16(af[i], b3f, acc3[i][j], 0, 0, 0);
            }
        }
        __syncthreads();
    }
    #pragma unroll
    for (int i = 0; i < 4; i++) {
        #pragma unroll
        for (int rg = 0; rg < 4; rg++) {
            int mm = mbase + wm * 64 + i * 16 + lq * 4 + rg;
            if (mm >= count) continue;
            int a = lists[e * T_TOK + mm];
            unsigned short* hrow = hgate + (size_t)a * F_DIM + nbase;
            #pragma unroll
            for (int j = 0; j < 4; j++) {
                float g = acc1[i][j][rg];
                float u = acc3[i][j][rg];
                float s = (g / (1.f + __expf(-g))) * u;
                hrow[wn * 64 + j * 16 + lr] = (unsigned short)f2bf(s);
            }
        }
    }
}

__global__ __launch_bounds__(256, 2)
void gemm2_f32(const unsigned short* __restrict__ hgate,
               const float* __restrict__ w2,
               const int* __restrict__ counts,
               const int* __restrict__ lists,
               const float* __restrict__ wgt,
               float* __restrict__ out) {
    const int e = blockIdx.z;
    const int count = counts[e];
    const int mbase = blockIdx.y * BM;
    if (mbase >= count) return;
    const int nbase = blockIdx.x * BN;

    __shared__ short As[BM * LDT];
    __shared__ short Bs[BN * LDT];

    const int tid = threadIdx.x;
    const int r = tid >> 1;
    const int half = tid & 1;

    const unsigned short* arow = nullptr;
    {
        int m = mbase + r;
        if (m < count) arow = hgate + (size_t)lists[e * T_TOK + m] * F_DIM;
    }
    const float* brow = w2 + ((size_t)e * H_DIM + (nbase + r)) * F_DIM;

    const int lane = tid & 63;
    const int wid = tid >> 6;
    const int wm = wid >> 1, wn = wid & 1;
    const int lr = lane & 15, lq = lane >> 4;

    f32x4 acc[4][4];
    #pragma unroll
    for (int i = 0; i < 4; i++)
        #pragma unroll
        for (int j = 0; j < 4; j++) acc[i][j] = (f32x4){0.f, 0.f, 0.f, 0.f};

    bf16x8 a2p[2];
    f32x4 bp[4];
    {
        const int koff = half * 16;
        if (arow) {
            const bf16x8* p = (const bf16x8*)(arow + koff);
            a2p[0] = p[0]; a2p[1] = p[1];
        }
        load16(bp, brow + koff);
    }
    short* adst = &As[r * LDT + half * 16];
    short* bdst = &Bs[r * LDT + half * 16];

    for (int k0 = 0; k0 < F_DIM; k0 += BK) {
        if (arow) {
            *(bf16x8*)adst = a2p[0];
            *((bf16x8*)adst + 1) = a2p[1];
        } else zero16_store(adst);
        cvt_store16(bp, bdst);
        __syncthreads();
        int kn = k0 + BK;
        if (kn < F_DIM) {
            const int koff = kn + half * 16;
            if (arow) {
                const bf16x8* p = (const bf16x8*)(arow + koff);
                a2p[0] = p[0]; a2p[1] = p[1];
            }
            load16(bp, brow + koff);
        }
        bf16x8 af[4];
        #pragma unroll
        for (int i = 0; i < 4; i++)
            af[i] = *(const bf16x8*)&As[(wm * 64 + i * 16 + lr) * LDT + lq * 8];
        #pragma unroll
        for (int j = 0; j < 4; j++) {
            bf16x8 bf = *(const bf16x8*)&Bs[(wn * 64 + j * 16 + lr) * LDT + lq * 8];
            #pragma unroll
            for (int i = 0; i < 4; i++)
                acc[i][j] = __builtin_amdgcn_mfma_f32_16x16x32_bf16(af[i], bf, acc[i][j], 0, 0, 0);
        }
        __syncthreads();
    }
    #pragma unroll
    for (int i = 0; i < 4; i++) {
        #pragma unroll
        for (int rg = 0; rg < 4; rg++) {
            int mm = mbase + wm * 64 + i * 16 + lq * 4 + rg;
            if (mm >= count) continue;
            int a = lists[e * T_TOK + mm];
            float wv = wgt[a];
            float* orow = out + (size_t)(a >> 1) * H_DIM + nbase;
            #pragma unroll
            for (int j = 0; j < 4; j++)
                atomicAdd(&orow[wn * 64 + j * 16 + lr], acc[i][j][rg] * wv);
        }
    }
}

// ---------------------------------------------------------------------------
extern "C" void kernel_launch(void* const* d_in, const int* in_sizes, int n_in,
                              void* d_out, int out_size, void* d_ws, size_t ws_size,
                              hipStream_t stream) {
    const float* x      = (const float*)d_in[0];
    const float* gate_w = (const float*)d_in[1];
    const float* w1     = (const float*)d_in[2];
    const float* w2     = (const float*)d_in[3];
    const float* w3     = (const float*)d_in[4];

    float* out    = (float*)d_out;
    float* logits = out + (size_t)T_TOK * H_DIM;

    const size_t W_ELEMS = (size_t)E_NUM * F_DIM * H_DIM;   // 29360128
    const size_t X_ELEMS = (size_t)T_TOK * H_DIM;           // 8388608

    // bf16 ws layout
    const size_t off_counts = 0;
    const size_t off_zbuf   = 256;            // 8 KB zeros (OOB staging target)
    const size_t off_lists  = 8704;
    const size_t off_wgt    = off_lists + (size_t)E_NUM * T_TOK * 4;        // 270848
    const size_t off_xbf    = off_wgt + (size_t)T_TOK * 2 * 4;              // 336384
    const size_t off_w1bf   = off_xbf + X_ELEMS * 2;
    const size_t off_w3bf   = off_w1bf + W_ELEMS * 2;
    const size_t off_w2bf   = off_w3bf + W_ELEMS * 2;
    const size_t off_hg     = off_w2bf + W_ELEMS * 2;
    const size_t NEED       = off_hg + (size_t)T_TOK * 2 * F_DIM * 2;       // ~296.3 MB

    char* ws = (char*)d_ws;

    if (ws_size >= NEED) {
        int*   counts = (int*)(ws + off_counts);
        unsigned short* zbuf = (unsigned short*)(ws + off_zbuf);
        int*   lists  = (int*)(ws + off_lists);
        float* wgt    = (float*)(ws + off_wgt);
        unsigned short* xbf  = (unsigned short*)(ws + off_xbf);
        unsigned short* w1bf = (unsigned short*)(ws + off_w1bf);
        unsigned short* w3bf = (unsigned short*)(ws + off_w3bf);
        unsigned short* w2bf = (unsigned short*)(ws + off_w2bf);
        unsigned short* hgate = (unsigned short*)(ws + off_hg);

        hipMemsetAsync(ws, 0, 8704, stream);   // counts + zbuf
        hipMemsetAsync(out, 0, (size_t)T_TOK * H_DIM * sizeof(float), stream);

        router_kernel<<<T_TOK / 4, 256, 0, stream>>>(x, gate_w, logits, counts, lists, wgt);

        cvt_bf16_kernel<<<2048, 256, 0, stream>>>(x,  xbf,  (int)(X_ELEMS / 8));
        cvt_bf16_kernel<<<4096, 256, 0, stream>>>(w1, w1bf, (int)(W_ELEMS / 8));
        cvt_bf16_kernel<<<4096, 256, 0, stream>>>(w3, w3bf, (int)(W_ELEMS / 8));
        cvt_bf16_kernel<<<4096, 256, 0, stream>>>(w2, w2bf, (int)(W_ELEMS / 8));

        gemm1_bf<<<dim3(T_TOK / BM, F_DIM / BN, E_NUM), 256, 0, stream>>>(
            xbf, w1bf, w3bf, counts, lists, zbuf, hgate);

        gemm2_bf<<<dim3(T_TOK / BM, H_DIM / BN, E_NUM), 256, 0, stream>>>(
            hgate, w2bf, counts, lists, wgt, zbuf, out);
    } else {
        // fallback: R2 layout + kernels
        int*   counts = (int*)(ws + 0);
        int*   lists  = (int*)(ws + 1024);
        float* wgt    = (float*)(ws + 1024 + (size_t)E_NUM * T_TOK * 4);
        unsigned short* hgate =
            (unsigned short*)(ws + 1024 + (size_t)E_NUM * T_TOK * 4 + (size_t)T_TOK * 2 * 4);

        hipMemsetAsync(counts, 0, E_NUM * sizeof(int), stream);
        hipMemsetAsync(out, 0, (size_t)T_TOK * H_DIM * sizeof(float), stream);

        router_kernel<<<T_TOK / 4, 256, 0, stream>>>(x, gate_w, logits, counts, lists, wgt);

        gemm1_f32<<<dim3(F_DIM / BN, T_TOK / BM, E_NUM), 256, 0, stream>>>(
            x, w1, w3, counts, lists, hgate);

        gemm2_f32<<<dim3(H_DIM / BN, T_TOK / BM, E_NUM), 256, 0, stream>>>(
            hgate, w2, counts, lists, wgt, out);
    }
}